// Round 2
// baseline (802.262 us; speedup 1.0000x reference)
//
#include <hip/hip_runtime.h>
#include <cstdint>
#include <cfloat>
#include <cmath>

#define NPTS 65536
#define NB 16
#define NS 20
#define KK 10

struct InitIdx { int idx[NB]; };

// ---------------- Kernel 1: farthest point sampling (exact JAX semantics) ---
// One block per batch. Per-thread dist_min[64] in registers. 20 serial steps.
__global__ __launch_bounds__(1024) void fps_kernel(const float* __restrict__ pcs,
                                                   float* __restrict__ seedpos,
                                                   float* __restrict__ out,
                                                   InitIdx init) {
    const int b = blockIdx.x;
    const int t = threadIdx.x;
    const float* __restrict__ base = pcs + (size_t)b * NPTS * 3;

    float dm[64];
#pragma unroll
    for (int i = 0; i < 64; ++i) dm[i] = 1e10f;

    __shared__ float s_val[16];
    __shared__ int   s_idx[16];
    __shared__ int   s_far;
    __shared__ float s_c[3];

    if (b == 0 && t == 0) out[0] = 0.0f;   // zero accumulator before kernel 2

    int far = init.idx[b];

    for (int s = 0; s < NS; ++s) {
        if (t == 0) {
            float cx = base[(size_t)far * 3 + 0];
            float cy = base[(size_t)far * 3 + 1];
            float cz = base[(size_t)far * 3 + 2];
            s_c[0] = cx; s_c[1] = cy; s_c[2] = cz;
            float* sp = seedpos + ((size_t)b * NS + s) * 3;
            sp[0] = cx; sp[1] = cy; sp[2] = cz;   // seed s = far BEFORE update
        }
        __syncthreads();
        const float cx = s_c[0], cy = s_c[1], cz = s_c[2];

        float bestv = -1.0f;
        int   besti = 0;
#pragma unroll
        for (int i = 0; i < 64; ++i) {
            const int n = i * 1024 + t;
            const float* p = base + (size_t)n * 3;
            // match XLA: rounded sub, rounded muls, sequential adds, NO fma
            float dx = __fsub_rn(p[0], cx);
            float dy = __fsub_rn(p[1], cy);
            float dz = __fsub_rn(p[2], cz);
            float d  = __fadd_rn(__fadd_rn(__fmul_rn(dx, dx), __fmul_rn(dy, dy)),
                                 __fmul_rn(dz, dz));
            dm[i] = fminf(dm[i], d);
            // first-occurrence argmax: strict >, n ascending within thread
            if (dm[i] > bestv) { bestv = dm[i]; besti = n; }
        }

        // wave reduce (64 lanes), tie-break: smaller index wins
#pragma unroll
        for (int off = 32; off >= 1; off >>= 1) {
            float ov = __shfl_down(bestv, off);
            int   oi = __shfl_down(besti, off);
            if (ov > bestv || (ov == bestv && oi < besti)) { bestv = ov; besti = oi; }
        }
        __syncthreads();
        if ((t & 63) == 0) { s_val[t >> 6] = bestv; s_idx[t >> 6] = besti; }
        __syncthreads();
        if (t == 0) {
            float bv = s_val[0]; int bi = s_idx[0];
            for (int w = 1; w < 16; ++w) {
                float v = s_val[w]; int ii = s_idx[w];
                if (v > bv || (v == bv && ii < bi)) { bv = v; bi = ii; }
            }
            s_far = bi;
        }
        __syncthreads();
        far = s_far;
    }
}

// ---------------- Kernel 2: per-seed 11 smallest distances + repulsion ------
// One block per (batch, seed). Per-thread sorted top-11 of squared distances,
// then block k-way merge. sqrt is monotone -> selection on sq == on dist.
__global__ __launch_bounds__(256) void knn_kernel(const float* __restrict__ pcs,
                                                  const float* __restrict__ seedpos,
                                                  float* __restrict__ out) {
    const int p = blockIdx.x;          // 0..319
    const int b = p / NS;
    const int t = threadIdx.x;
    const float* __restrict__ base = pcs + (size_t)b * NPTS * 3;
    const float cx = seedpos[(size_t)p * 3 + 0];
    const float cy = seedpos[(size_t)p * 3 + 1];
    const float cz = seedpos[(size_t)p * 3 + 2];

    float lst[11];
#pragma unroll
    for (int j = 0; j < 11; ++j) lst[j] = FLT_MAX;

    for (int i = 0; i < 256; ++i) {
        const int n = i * 256 + t;
        const float* q = base + (size_t)n * 3;
        float dx = __fsub_rn(q[0], cx);
        float dy = __fsub_rn(q[1], cy);
        float dz = __fsub_rn(q[2], cz);
        float sq = __fadd_rn(__fadd_rn(__fmul_rn(dx, dx), __fmul_rn(dy, dy)),
                             __fmul_rn(dz, dz));
        if (sq < lst[10]) {
            lst[10] = sq;
            // fully-unrolled bubble-insert (keeps indices compile-time const)
#pragma unroll
            for (int j = 10; j > 0; --j) {
                float a = lst[j - 1], c = lst[j];
                lst[j - 1] = fminf(a, c);
                lst[j]     = fmaxf(a, c);
            }
        }
    }

    __shared__ float lists[256][11];
#pragma unroll
    for (int j = 0; j < 11; ++j) lists[t][j] = lst[j];
    __shared__ float rv[256];
    __shared__ int   ri[256];
    __shared__ float s_sel[11];
    __syncthreads();

    int ptr = 0;
    for (int r = 0; r < 11; ++r) {
        float v = (ptr < 11) ? lists[t][ptr] : FLT_MAX;
        rv[t] = v; ri[t] = t;
        __syncthreads();
        for (int off = 128; off >= 1; off >>= 1) {
            if (t < off) {
                float o = rv[t + off]; int oi = ri[t + off];
                if (o < rv[t]) { rv[t] = o; ri[t] = oi; }
            }
            __syncthreads();
        }
        if (t == 0) s_sel[r] = rv[0];
        const int win = ri[0];
        __syncthreads();          // protect rv/ri before next round overwrites
        if (t == win) ptr++;
    }

    if (t == 0) {
        const float HH = (float)(0.01 * 0.01);   // JAX weak-typed scalar H*H
        float acc = 0.0f;
#pragma unroll
        for (int r = 1; r <= KK; ++r) {          // drop s_sel[0] (self, ==0)
            float sq = s_sel[r];
            float d  = (sq == 0.0f) ? 0.0f : __fsqrt_rn(sq);
            float q2 = __fmul_rn(d, d);
            float w  = expf(__fdiv_rn(-q2, HH));
            acc = __fadd_rn(acc, -__fmul_rn(d, w));
        }
        atomicAdd(out, acc * 0.0625f);           // mean over B=16
    }
}

// ---------------- Host: JAX threefry2x32 (partitionable mode) ---------------
static inline uint32_t rotl32(uint32_t x, uint32_t d) { return (x << d) | (x >> (32 - d)); }

static void tf2x32(uint32_t k0, uint32_t k1, uint32_t x0, uint32_t x1,
                   uint32_t& y0, uint32_t& y1) {
    const uint32_t ks[3] = { k0, k1, k0 ^ k1 ^ 0x1BD11BDAu };
    const uint32_t rotA[4] = { 13, 15, 26, 6 };
    const uint32_t rotB[4] = { 17, 29, 16, 24 };
    uint32_t v0 = x0 + ks[0], v1 = x1 + ks[1];
    for (int i = 0; i < 5; ++i) {
        const uint32_t* rot = (i % 2 == 0) ? rotA : rotB;
        for (int j = 0; j < 4; ++j) {
            v0 += v1;
            v1 = rotl32(v1, rot[j]);
            v1 ^= v0;
        }
        v0 += ks[(i + 1) % 3];
        v1 += ks[(i + 2) % 3] + (uint32_t)(i + 1);
    }
    y0 = v0; y1 = v1;
}

extern "C" void kernel_launch(void* const* d_in, const int* in_sizes, int n_in,
                              void* d_out, int out_size, void* d_ws, size_t ws_size,
                              hipStream_t stream) {
    const float* pcs = (const float*)d_in[0];
    float* out = (float*)d_out;
    float* seedpos = (float*)d_ws;   // 16*20*3 floats

    // jax.random.key(1) -> threefry key (0,1).
    // Modern JAX defaults jax_threefry_partitionable=True:
    //   split(key,2) "foldlike": keys[i] = threefry(key, (hi=0, lo=i)),
    //                            both output words -> k2 = threefry((0,1),(0,1))
    //   random_bits(k2,32,(16,)): counters (hi,lo)=(0,i), 32-bit out = y0 ^ y1
    uint32_t k2_0, k2_1;
    tf2x32(0u, 1u, 0u, 1u, k2_0, k2_1);

    // randint(k,(16,),0,65536): span=2^16 -> multiplier=0 ->
    // result = random_bits(k2) & 0xFFFF
    InitIdx init;
    for (int i = 0; i < NB; ++i) {
        uint32_t y0, y1;
        tf2x32(k2_0, k2_1, 0u, (uint32_t)i, y0, y1);
        init.idx[i] = (int)((y0 ^ y1) & 0xFFFFu);
    }

    hipLaunchKernelGGL(fps_kernel, dim3(NB), dim3(1024), 0, stream,
                       pcs, seedpos, out, init);
    hipLaunchKernelGGL(knn_kernel, dim3(NB * NS), dim3(256), 0, stream,
                       pcs, seedpos, out);
}

// Round 3
// 682.586 us; speedup vs baseline: 1.1753x; 1.1753x over previous
//
#include <hip/hip_runtime.h>
#include <cstdint>
#include <cfloat>
#include <cmath>

#define NPTS 65536
#define NB 16
#define NS 20
#define KK 10

struct InitIdx { int idx[NB]; };

// ---------------- Kernel 1: farthest point sampling (exact JAX semantics) ---
// One block per batch, 1024 threads, dm[64] held in VGPRs.
// __launch_bounds__(1024, 4): 4 waves/EU = 16 waves/CU = this one block ->
// VGPR cap 128, so dm[] stays in registers (R2 profile showed 64-VGPR cap
// spilled dm to scratch: 23.7 MB of HBM writes per dispatch).
__global__ __launch_bounds__(1024, 4) void fps_kernel(const float* __restrict__ pcs,
                                                      float* __restrict__ seedpos,
                                                      float* __restrict__ out,
                                                      InitIdx init) {
    const int b = blockIdx.x;
    const int t = threadIdx.x;
    const float* __restrict__ base = pcs + (size_t)b * NPTS * 3;

    float dm[64];
#pragma unroll
    for (int i = 0; i < 64; ++i) dm[i] = 1e10f;

    __shared__ float s_val[16];
    __shared__ int   s_idx[16];
    __shared__ int   s_far;
    __shared__ float s_c[3];

    if (b == 0 && t == 0) out[0] = 0.0f;   // zero accumulator before kernel 2

    int far = init.idx[b];

    for (int s = 0; s < NS; ++s) {
        if (t == 0) {
            float cx = base[(size_t)far * 3 + 0];
            float cy = base[(size_t)far * 3 + 1];
            float cz = base[(size_t)far * 3 + 2];
            s_c[0] = cx; s_c[1] = cy; s_c[2] = cz;
            float* sp = seedpos + ((size_t)b * NS + s) * 3;
            sp[0] = cx; sp[1] = cy; sp[2] = cz;   // seed s = far BEFORE update
        }
        __syncthreads();
        if (s == NS - 1) break;            // 20th min-update/argmax is unused
        const float cx = s_c[0], cy = s_c[1], cz = s_c[2];

        float bestv = -1.0f;
        int   besti = 0;
#pragma unroll
        for (int i = 0; i < 64; ++i) {
            const int n = i * 1024 + t;
            const float* p = base + (size_t)n * 3;
            // match XLA: rounded sub, rounded muls, sequential adds, NO fma
            float dx = __fsub_rn(p[0], cx);
            float dy = __fsub_rn(p[1], cy);
            float dz = __fsub_rn(p[2], cz);
            float d  = __fadd_rn(__fadd_rn(__fmul_rn(dx, dx), __fmul_rn(dy, dy)),
                                 __fmul_rn(dz, dz));
            dm[i] = fminf(dm[i], d);
            // first-occurrence argmax: strict >, n ascending within thread
            if (dm[i] > bestv) { bestv = dm[i]; besti = n; }
        }

        // wave reduce (64 lanes), tie-break: smaller index wins
#pragma unroll
        for (int off = 32; off >= 1; off >>= 1) {
            float ov = __shfl_down(bestv, off);
            int   oi = __shfl_down(besti, off);
            if (ov > bestv || (ov == bestv && oi < besti)) { bestv = ov; besti = oi; }
        }
        __syncthreads();
        if ((t & 63) == 0) { s_val[t >> 6] = bestv; s_idx[t >> 6] = besti; }
        __syncthreads();
        if (t == 0) {
            float bv = s_val[0]; int bi = s_idx[0];
            for (int w = 1; w < 16; ++w) {
                float v = s_val[w]; int ii = s_idx[w];
                if (v > bv || (v == bv && ii < bi)) { bv = v; bi = ii; }
            }
            s_far = bi;
        }
        __syncthreads();
        far = s_far;
    }
}

// ---------------- Kernel 2: per-seed 11 smallest distances + repulsion ------
// One block (1024 thr) per (batch, seed). Per-thread sorted top-11 of squared
// distances over 64 points, wave-level shuffle merge, single-wave final merge.
// sqrt is monotone -> selection on sq == selection on dist.
__global__ __launch_bounds__(1024) void knn_kernel(const float* __restrict__ pcs,
                                                   const float* __restrict__ seedpos,
                                                   float* __restrict__ out) {
    const int p = blockIdx.x;          // 0..319
    const int b = p / NS;
    const int t = threadIdx.x;
    const int lane = t & 63;
    const int w = t >> 6;              // wave id 0..15
    const float* __restrict__ base = pcs + (size_t)b * NPTS * 3;
    const float cx = seedpos[(size_t)p * 3 + 0];
    const float cy = seedpos[(size_t)p * 3 + 1];
    const float cz = seedpos[(size_t)p * 3 + 2];

    float lst[11];
#pragma unroll
    for (int j = 0; j < 11; ++j) lst[j] = FLT_MAX;

#pragma unroll 8
    for (int i = 0; i < 64; ++i) {
        const int n = i * 1024 + t;
        const float* q = base + (size_t)n * 3;
        float dx = __fsub_rn(q[0], cx);
        float dy = __fsub_rn(q[1], cy);
        float dz = __fsub_rn(q[2], cz);
        float sq = __fadd_rn(__fadd_rn(__fmul_rn(dx, dx), __fmul_rn(dy, dy)),
                             __fmul_rn(dz, dz));
        if (sq < lst[10]) {
            lst[10] = sq;
#pragma unroll
            for (int j = 10; j > 0; --j) {
                float a = lst[j - 1], c = lst[j];
                lst[j - 1] = fminf(a, c);
                lst[j]     = fmaxf(a, c);
            }
        }
    }

    // ---- wave-level top-11: 11 rounds of (wave-min of heads, pop one copy) --
    __shared__ float s_top[16][11];
    for (int r = 0; r < 11; ++r) {
        float v = lst[0];
#pragma unroll
        for (int off = 32; off >= 1; off >>= 1) v = fminf(v, __shfl_xor(v, off));
        unsigned long long m = __ballot(lst[0] == v);
        if (lane == __ffsll((unsigned long long)m) - 1) {
            // pop exactly one copy (exact under duplicate values)
#pragma unroll
            for (int j = 0; j < 10; ++j) lst[j] = lst[j + 1];
            lst[10] = FLT_MAX;
        }
        if (lane == 0) s_top[w][r] = v;
    }
    __syncthreads();

    // ---- final merge: wave 0 merges 16 lists x 11 = 176 values -------------
    if (w == 0) {
        const float* flat = &s_top[0][0];
        float a0 = flat[lane];                                  // lane < 176
        float a1 = flat[lane + 64];                             // <176
        float a2 = (lane + 128 < 176) ? flat[lane + 128] : FLT_MAX;

        const float HH = (float)(0.01 * 0.01);   // JAX weak-typed scalar H*H
        float acc = 0.0f;
        for (int r = 0; r < 11; ++r) {
            float mymin = fminf(a0, fminf(a1, a2));
            float v = mymin;
#pragma unroll
            for (int off = 32; off >= 1; off >>= 1) v = fminf(v, __shfl_xor(v, off));
            unsigned long long m = __ballot(mymin == v);
            if (lane == __ffsll(m) - 1) {
                if (a0 == v)      a0 = FLT_MAX;
                else if (a1 == v) a1 = FLT_MAX;
                else              a2 = FLT_MAX;
            }
            if (lane == 0 && r >= 1) {           // r==0 is self (dist 0)
                float sq = v;
                float d  = (sq == 0.0f) ? 0.0f : __fsqrt_rn(sq);
                float q2 = __fmul_rn(d, d);
                float wt = expf(__fdiv_rn(-q2, HH));
                acc = __fadd_rn(acc, -__fmul_rn(d, wt));
            }
        }
        if (lane == 0) atomicAdd(out, acc * 0.0625f);   // mean over B=16
    }
}

// ---------------- Host: JAX threefry2x32 (partitionable mode) ---------------
static inline uint32_t rotl32(uint32_t x, uint32_t d) { return (x << d) | (x >> (32 - d)); }

static void tf2x32(uint32_t k0, uint32_t k1, uint32_t x0, uint32_t x1,
                   uint32_t& y0, uint32_t& y1) {
    const uint32_t ks[3] = { k0, k1, k0 ^ k1 ^ 0x1BD11BDAu };
    const uint32_t rotA[4] = { 13, 15, 26, 6 };
    const uint32_t rotB[4] = { 17, 29, 16, 24 };
    uint32_t v0 = x0 + ks[0], v1 = x1 + ks[1];
    for (int i = 0; i < 5; ++i) {
        const uint32_t* rot = (i % 2 == 0) ? rotA : rotB;
        for (int j = 0; j < 4; ++j) {
            v0 += v1;
            v1 = rotl32(v1, rot[j]);
            v1 ^= v0;
        }
        v0 += ks[(i + 1) % 3];
        v1 += ks[(i + 2) % 3] + (uint32_t)(i + 1);
    }
    y0 = v0; y1 = v1;
}

extern "C" void kernel_launch(void* const* d_in, const int* in_sizes, int n_in,
                              void* d_out, int out_size, void* d_ws, size_t ws_size,
                              hipStream_t stream) {
    const float* pcs = (const float*)d_in[0];
    float* out = (float*)d_out;
    float* seedpos = (float*)d_ws;   // 16*20*3 floats

    // jax.random.key(1) -> threefry key (0,1).
    // jax_threefry_partitionable=True (modern default):
    //   split(key,2) foldlike: k2 = threefry((0,1), (hi=0, lo=1)), both words
    //   random_bits(k2,32,(16,)): counters (hi,lo)=(0,i), out = y0 ^ y1
    uint32_t k2_0, k2_1;
    tf2x32(0u, 1u, 0u, 1u, k2_0, k2_1);

    InitIdx init;
    for (int i = 0; i < NB; ++i) {
        uint32_t y0, y1;
        tf2x32(k2_0, k2_1, 0u, (uint32_t)i, y0, y1);
        init.idx[i] = (int)((y0 ^ y1) & 0xFFFFu);   // randint span 2^16 -> mask
    }

    hipLaunchKernelGGL(fps_kernel, dim3(NB), dim3(1024), 0, stream,
                       pcs, seedpos, out, init);
    hipLaunchKernelGGL(knn_kernel, dim3(NB * NS), dim3(1024), 0, stream,
                       pcs, seedpos, out);
}

// Round 4
// 393.383 us; speedup vs baseline: 2.0394x; 1.7352x over previous
//
#include <hip/hip_runtime.h>
#include <cstdint>
#include <cfloat>
#include <cmath>

#define NPTS 65536
#define NB 16
#define NS 20
#define KK 10
#define FPB 16      // FPS blocks per batch
#define PPT 4       // points per thread (16 blk * 1024 thr * 4 = 65536)

struct InitIdx { int idx[NB]; };

// ---------------- Kernel 1: distributed FPS (exact JAX semantics) -----------
// 256 blocks (16 per batch) x 1024 threads, 4 points/thread held ENTIRELY in
// registers (coords + running min). Cross-block argmax per step via packed
// u64 atomicMax (val<<32 | ~idx : max val, tie -> smallest idx = JAX argmax
// first-occurrence), then a per-batch atomic-counter barrier (16 arrivals).
// Co-residency: 4096 waves, ~48 VGPR -> >=256 block slots under any packing.
__global__ __launch_bounds__(1024) void fps_kernel(const float* __restrict__ pcs,
                                                   int* __restrict__ seeds,
                                                   unsigned long long* __restrict__ keys,
                                                   unsigned int* __restrict__ cnt,
                                                   InitIdx init) {
    const int bb = blockIdx.x;
    const int b  = bb >> 4;
    const int j  = bb & 15;
    const int t  = threadIdx.x;
    const int lane = t & 63;
    const int w    = t >> 6;
    const float* __restrict__ base = pcs + (size_t)b * NPTS * 3;
    const int pbase = j * 4096 + t;

    float x[PPT], y[PPT], z[PPT], dmv[PPT];
#pragma unroll
    for (int q = 0; q < PPT; ++q) {
        const float* p = base + (size_t)(pbase + q * 1024) * 3;
        x[q] = p[0]; y[q] = p[1]; z[q] = p[2];
        dmv[q] = 1e10f;
    }

    __shared__ float s_val[16];
    __shared__ int   s_idx[16];
    __shared__ int   s_far;

    int far = init.idx[b];

    for (int s = 0; s < NS; ++s) {
        if (j == 0 && t == 0) seeds[b * NS + s] = far;   // seed s = far BEFORE update
        if (s == NS - 1) break;                          // last update/argmax unused

        const float* c = base + (size_t)far * 3;         // uniform, L1/L2 hit
        const float cx = c[0], cy = c[1], cz = c[2];

        float bestv = -1.0f;
        int   besti = 0;
#pragma unroll
        for (int q = 0; q < PPT; ++q) {
            // match XLA: rounded sub/mul, sequential adds, NO fma contraction
            float dx = __fsub_rn(x[q], cx);
            float dy = __fsub_rn(y[q], cy);
            float dz = __fsub_rn(z[q], cz);
            float d  = __fadd_rn(__fadd_rn(__fmul_rn(dx, dx), __fmul_rn(dy, dy)),
                                 __fmul_rn(dz, dz));
            dmv[q] = fminf(dmv[q], d);
            // q ascending = index ascending; strict > keeps first occurrence
            if (dmv[q] > bestv) { bestv = dmv[q]; besti = pbase + q * 1024; }
        }

        // wave argmax (strict >, tie -> smaller index)
#pragma unroll
        for (int off = 32; off >= 1; off >>= 1) {
            float ov = __shfl_down(bestv, off);
            int   oi = __shfl_down(besti, off);
            if (ov > bestv || (ov == bestv && oi < besti)) { bestv = ov; besti = oi; }
        }
        if (lane == 0) { s_val[w] = bestv; s_idx[w] = besti; }
        __syncthreads();

        if (t == 0) {
            float bv = s_val[0]; int bi = s_idx[0];
            for (int k = 1; k < 16; ++k) {
                float v = s_val[k]; int ii = s_idx[k];
                if (v > bv || (v == bv && ii < bi)) { bv = v; bi = ii; }
            }
            // packed key: monotone for bv >= 0; tie -> larger (~idx) = smaller idx
            unsigned long long packed =
                ((unsigned long long)__float_as_uint(bv) << 32) |
                (unsigned long long)(0xFFFFFFFFu - (unsigned int)bi);
            unsigned long long* kp = keys + (b * NS + s);
            atomicMax(kp, packed);
            __threadfence();                       // release: key before arrive
            atomicAdd(&cnt[b], 1u);
            const unsigned int target = (unsigned int)(FPB * (s + 1));
            while (atomicAdd(&cnt[b], 0u) < target) { }   // device-scope spin
            __threadfence();                       // acquire: arrive before key read
            unsigned long long kk = atomicAdd(kp, 0ULL);
            s_far = (int)(0xFFFFFFFFu - (unsigned int)(kk & 0xFFFFFFFFull));
        }
        __syncthreads();
        far = s_far;
    }
}

// ---------------- Kernel 2: per-seed 11 smallest distances + repulsion ------
// One block (1024 thr) per (batch, seed). Per-thread sorted top-11 of squared
// distances over 64 points, wave-level shuffle merge, single-wave final merge.
// sqrt is monotone -> selection on sq == selection on dist.
__global__ __launch_bounds__(1024) void knn_kernel(const float* __restrict__ pcs,
                                                   const int* __restrict__ seeds,
                                                   float* __restrict__ out) {
    const int p = blockIdx.x;          // 0..319
    const int b = p / NS;
    const int t = threadIdx.x;
    const int lane = t & 63;
    const int w = t >> 6;              // wave id 0..15
    const float* __restrict__ base = pcs + (size_t)b * NPTS * 3;
    const int sidx = seeds[p];
    const float cx = base[(size_t)sidx * 3 + 0];
    const float cy = base[(size_t)sidx * 3 + 1];
    const float cz = base[(size_t)sidx * 3 + 2];

    float lst[11];
#pragma unroll
    for (int jj = 0; jj < 11; ++jj) lst[jj] = FLT_MAX;

#pragma unroll 8
    for (int i = 0; i < 64; ++i) {
        const int n = i * 1024 + t;
        const float* q = base + (size_t)n * 3;
        float dx = __fsub_rn(q[0], cx);
        float dy = __fsub_rn(q[1], cy);
        float dz = __fsub_rn(q[2], cz);
        float sq = __fadd_rn(__fadd_rn(__fmul_rn(dx, dx), __fmul_rn(dy, dy)),
                             __fmul_rn(dz, dz));
        if (sq < lst[10]) {
            lst[10] = sq;
#pragma unroll
            for (int jj = 10; jj > 0; --jj) {
                float a = lst[jj - 1], c = lst[jj];
                lst[jj - 1] = fminf(a, c);
                lst[jj]     = fmaxf(a, c);
            }
        }
    }

    // ---- wave-level top-11: 11 rounds of (wave-min of heads, pop one copy) --
    __shared__ float s_top[16][11];
    for (int r = 0; r < 11; ++r) {
        float v = lst[0];
#pragma unroll
        for (int off = 32; off >= 1; off >>= 1) v = fminf(v, __shfl_xor(v, off));
        unsigned long long m = __ballot(lst[0] == v);
        if (lane == __ffsll((unsigned long long)m) - 1) {
#pragma unroll
            for (int jj = 0; jj < 10; ++jj) lst[jj] = lst[jj + 1];
            lst[10] = FLT_MAX;
        }
        if (lane == 0) s_top[w][r] = v;
    }
    __syncthreads();

    // ---- final merge: wave 0 merges 16 lists x 11 = 176 values -------------
    if (w == 0) {
        const float* flat = &s_top[0][0];
        float a0 = flat[lane];
        float a1 = flat[lane + 64];
        float a2 = (lane + 128 < 176) ? flat[lane + 128] : FLT_MAX;

        const float HH = (float)(0.01 * 0.01);   // JAX weak-typed scalar H*H
        float acc = 0.0f;
        for (int r = 0; r < 11; ++r) {
            float mymin = fminf(a0, fminf(a1, a2));
            float v = mymin;
#pragma unroll
            for (int off = 32; off >= 1; off >>= 1) v = fminf(v, __shfl_xor(v, off));
            unsigned long long m = __ballot(mymin == v);
            if (lane == __ffsll(m) - 1) {
                if (a0 == v)      a0 = FLT_MAX;
                else if (a1 == v) a1 = FLT_MAX;
                else              a2 = FLT_MAX;
            }
            if (lane == 0 && r >= 1) {           // r==0 is self (dist 0)
                float sq = v;
                float d  = (sq == 0.0f) ? 0.0f : __fsqrt_rn(sq);
                float q2 = __fmul_rn(d, d);
                float wt = expf(__fdiv_rn(-q2, HH));
                acc = __fadd_rn(acc, -__fmul_rn(d, wt));
            }
        }
        if (lane == 0) atomicAdd(out, acc * 0.0625f);   // mean over B=16
    }
}

// ---------------- Host: JAX threefry2x32 (partitionable mode) ---------------
static inline uint32_t rotl32(uint32_t x, uint32_t d) { return (x << d) | (x >> (32 - d)); }

static void tf2x32(uint32_t k0, uint32_t k1, uint32_t x0, uint32_t x1,
                   uint32_t& y0, uint32_t& y1) {
    const uint32_t ks[3] = { k0, k1, k0 ^ k1 ^ 0x1BD11BDAu };
    const uint32_t rotA[4] = { 13, 15, 26, 6 };
    const uint32_t rotB[4] = { 17, 29, 16, 24 };
    uint32_t v0 = x0 + ks[0], v1 = x1 + ks[1];
    for (int i = 0; i < 5; ++i) {
        const uint32_t* rot = (i % 2 == 0) ? rotA : rotB;
        for (int j = 0; j < 4; ++j) {
            v0 += v1;
            v1 = rotl32(v1, rot[j]);
            v1 ^= v0;
        }
        v0 += ks[(i + 1) % 3];
        v1 += ks[(i + 2) % 3] + (uint32_t)(i + 1);
    }
    y0 = v0; y1 = v1;
}

extern "C" void kernel_launch(void* const* d_in, const int* in_sizes, int n_in,
                              void* d_out, int out_size, void* d_ws, size_t ws_size,
                              hipStream_t stream) {
    const float* pcs = (const float*)d_in[0];
    float* out = (float*)d_out;

    // ws layout: [0,1280) seeds (int), [2048,4608) keys (u64), [8192,8256) cnt
    int* seeds               = (int*)d_ws;
    unsigned long long* keys = (unsigned long long*)((char*)d_ws + 2048);
    unsigned int* cnt        = (unsigned int*)((char*)d_ws + 8192);

    // jax.random.key(1) -> threefry key (0,1), partitionable mode:
    //   split foldlike: k2 = threefry((0,1),(0,1)) both words
    //   random_bits: counters (0,i), out = y0 ^ y1; randint span 2^16 -> mask
    uint32_t k2_0, k2_1;
    tf2x32(0u, 1u, 0u, 1u, k2_0, k2_1);
    InitIdx init;
    for (int i = 0; i < NB; ++i) {
        uint32_t y0, y1;
        tf2x32(k2_0, k2_1, 0u, (uint32_t)i, y0, y1);
        init.idx[i] = (int)((y0 ^ y1) & 0xFFFFu);
    }

    hipMemsetAsync(d_ws, 0, 9216, stream);   // zero seeds/keys/cnt every call
    hipMemsetAsync(d_out, 0, sizeof(float), stream);

    hipLaunchKernelGGL(fps_kernel, dim3(NB * FPB), dim3(1024), 0, stream,
                       pcs, seeds, keys, cnt, init);
    hipLaunchKernelGGL(knn_kernel, dim3(NB * NS), dim3(1024), 0, stream,
                       pcs, seeds, out);
}

// Round 5
// 130.123 us; speedup vs baseline: 6.1654x; 3.0232x over previous
//
#include <hip/hip_runtime.h>
#include <cstdint>
#include <cfloat>
#include <cmath>

#define NPTS 65536
#define NB 16
#define NS 20
#define KK 10
#define FPB 16      // FPS blocks per batch
#define PPT 4       // points per thread (16 blk * 1024 thr * 4 = 65536)

struct InitIdx { int idx[NB]; };

// ---------------- Kernel 1: distributed FPS (exact JAX semantics) -----------
// 256 blocks (16 per batch) x 1024 threads, 4 points/thread in registers.
// Cross-block argmax per step: each block's leader publishes a packed u64
// (fbits(val)<<32 | ~idx -> max = larger val, tie -> smaller idx = JAX argmax
// first-occurrence) into a per-(batch,step,block) slot with an agent-scope
// relaxed atomic STORE (payload is self-contained -> no fence needed); all
// blocks poll the 16 slots with agent-scope atomic LOADS (no RMW contention)
// and shuffle-reduce the max. Slots re-zeroed per call by captured memset.
__global__ __launch_bounds__(1024) void fps_kernel(const float* __restrict__ pcs,
                                                   int* __restrict__ seeds,
                                                   unsigned long long* __restrict__ slots,
                                                   InitIdx init) {
    const int bb = blockIdx.x;
    const int b  = bb >> 4;
    const int j  = bb & 15;
    const int t  = threadIdx.x;
    const int lane = t & 63;
    const int w    = t >> 6;
    const float* __restrict__ base = pcs + (size_t)b * NPTS * 3;
    const int pbase = j * 4096 + t;

    float x[PPT], y[PPT], z[PPT], dmv[PPT];
#pragma unroll
    for (int q = 0; q < PPT; ++q) {
        const float* p = base + (size_t)(pbase + q * 1024) * 3;
        x[q] = p[0]; y[q] = p[1]; z[q] = p[2];
        dmv[q] = 1e10f;
    }

    __shared__ float s_val[16];
    __shared__ int   s_idx[16];
    __shared__ int   s_far;

    int far = init.idx[b];

    for (int s = 0; s < NS; ++s) {
        if (j == 0 && t == 0) seeds[b * NS + s] = far;   // seed s = far BEFORE update
        if (s == NS - 1) break;                          // last update/argmax unused

        const float* c = base + (size_t)far * 3;         // uniform, L1/L2 hit
        const float cx = c[0], cy = c[1], cz = c[2];

        float bestv = -1.0f;
        int   besti = 0;
#pragma unroll
        for (int q = 0; q < PPT; ++q) {
            // match XLA: rounded sub/mul, sequential adds, NO fma contraction
            float dx = __fsub_rn(x[q], cx);
            float dy = __fsub_rn(y[q], cy);
            float dz = __fsub_rn(z[q], cz);
            float d  = __fadd_rn(__fadd_rn(__fmul_rn(dx, dx), __fmul_rn(dy, dy)),
                                 __fmul_rn(dz, dz));
            dmv[q] = fminf(dmv[q], d);
            // q ascending = index ascending; strict > keeps first occurrence
            if (dmv[q] > bestv) { bestv = dmv[q]; besti = pbase + q * 1024; }
        }

        // wave argmax (strict >, tie -> smaller index)
#pragma unroll
        for (int off = 32; off >= 1; off >>= 1) {
            float ov = __shfl_down(bestv, off);
            int   oi = __shfl_down(besti, off);
            if (ov > bestv || (ov == bestv && oi < besti)) { bestv = ov; besti = oi; }
        }
        if (lane == 0) { s_val[w] = bestv; s_idx[w] = besti; }
        __syncthreads();

        unsigned long long* sp = slots + ((size_t)(b * NS + s) << 4);
        if (w == 0) {
            if (lane == 0) {
                float bv = s_val[0]; int bi = s_idx[0];
                for (int k = 1; k < 16; ++k) {
                    float v = s_val[k]; int ii = s_idx[k];
                    if (v > bv || (v == bv && ii < bi)) { bv = v; bi = ii; }
                }
                // packed: monotone for bv >= 0; tie -> larger ~idx = smaller idx.
                // Always nonzero (low word = ~idx != 0 for idx < 2^32-1).
                unsigned long long packed =
                    ((unsigned long long)__float_as_uint(bv) << 32) |
                    (unsigned long long)(0xFFFFFFFFu - (unsigned int)bi);
                __hip_atomic_store(&sp[j], packed, __ATOMIC_RELAXED,
                                   __HIP_MEMORY_SCOPE_AGENT);
            }
            // poll: lane l watches slot l&15 (coalesced pure loads, no RMW)
            unsigned long long v;
            do {
                v = __hip_atomic_load(&sp[lane & 15], __ATOMIC_RELAXED,
                                      __HIP_MEMORY_SCOPE_AGENT);
                if (v == 0ULL) __builtin_amdgcn_s_sleep(1);
            } while (v == 0ULL);
            // wave max-reduce of packed keys (split 64-bit shuffle)
#pragma unroll
            for (int off = 32; off >= 1; off >>= 1) {
                unsigned int lo = (unsigned int)(v & 0xFFFFFFFFull);
                unsigned int hi = (unsigned int)(v >> 32);
                unsigned int olo = (unsigned int)__shfl_xor((int)lo, off);
                unsigned int ohi = (unsigned int)__shfl_xor((int)hi, off);
                unsigned long long o = ((unsigned long long)ohi << 32) | olo;
                if (o > v) v = o;
            }
            if (lane == 0)
                s_far = (int)(0xFFFFFFFFu - (unsigned int)(v & 0xFFFFFFFFull));
        }
        __syncthreads();
        far = s_far;
    }
}

// ---------------- Kernel 2: per-seed 11 smallest distances + repulsion ------
// One block (1024 thr) per (batch, seed). Per-thread sorted top-11 of squared
// distances over 64 points, wave-level shuffle merge, single-wave final merge.
// sqrt is monotone -> selection on sq == selection on dist.
__global__ __launch_bounds__(1024) void knn_kernel(const float* __restrict__ pcs,
                                                   const int* __restrict__ seeds,
                                                   float* __restrict__ out) {
    const int p = blockIdx.x;          // 0..319
    const int b = p / NS;
    const int t = threadIdx.x;
    const int lane = t & 63;
    const int w = t >> 6;              // wave id 0..15
    const float* __restrict__ base = pcs + (size_t)b * NPTS * 3;
    const int sidx = seeds[p];
    const float cx = base[(size_t)sidx * 3 + 0];
    const float cy = base[(size_t)sidx * 3 + 1];
    const float cz = base[(size_t)sidx * 3 + 2];

    float lst[11];
#pragma unroll
    for (int jj = 0; jj < 11; ++jj) lst[jj] = FLT_MAX;

#pragma unroll 8
    for (int i = 0; i < 64; ++i) {
        const int n = i * 1024 + t;
        const float* q = base + (size_t)n * 3;
        float dx = __fsub_rn(q[0], cx);
        float dy = __fsub_rn(q[1], cy);
        float dz = __fsub_rn(q[2], cz);
        float sq = __fadd_rn(__fadd_rn(__fmul_rn(dx, dx), __fmul_rn(dy, dy)),
                             __fmul_rn(dz, dz));
        if (sq < lst[10]) {
            lst[10] = sq;
#pragma unroll
            for (int jj = 10; jj > 0; --jj) {
                float a = lst[jj - 1], c = lst[jj];
                lst[jj - 1] = fminf(a, c);
                lst[jj]     = fmaxf(a, c);
            }
        }
    }

    // ---- wave-level top-11: 11 rounds of (wave-min of heads, pop one copy) --
    __shared__ float s_top[16][11];
    for (int r = 0; r < 11; ++r) {
        float v = lst[0];
#pragma unroll
        for (int off = 32; off >= 1; off >>= 1) v = fminf(v, __shfl_xor(v, off));
        unsigned long long m = __ballot(lst[0] == v);
        if (lane == __ffsll((unsigned long long)m) - 1) {
#pragma unroll
            for (int jj = 0; jj < 10; ++jj) lst[jj] = lst[jj + 1];
            lst[10] = FLT_MAX;
        }
        if (lane == 0) s_top[w][r] = v;
    }
    __syncthreads();

    // ---- final merge: wave 0 merges 16 lists x 11 = 176 values -------------
    if (w == 0) {
        const float* flat = &s_top[0][0];
        float a0 = flat[lane];
        float a1 = flat[lane + 64];
        float a2 = (lane + 128 < 176) ? flat[lane + 128] : FLT_MAX;

        const float HH = (float)(0.01 * 0.01);   // JAX weak-typed scalar H*H
        float acc = 0.0f;
        for (int r = 0; r < 11; ++r) {
            float mymin = fminf(a0, fminf(a1, a2));
            float v = mymin;
#pragma unroll
            for (int off = 32; off >= 1; off >>= 1) v = fminf(v, __shfl_xor(v, off));
            unsigned long long m = __ballot(mymin == v);
            if (lane == __ffsll(m) - 1) {
                if (a0 == v)      a0 = FLT_MAX;
                else if (a1 == v) a1 = FLT_MAX;
                else              a2 = FLT_MAX;
            }
            if (lane == 0 && r >= 1) {           // r==0 is self (dist 0)
                float sq = v;
                float d  = (sq == 0.0f) ? 0.0f : __fsqrt_rn(sq);
                float q2 = __fmul_rn(d, d);
                float wt = expf(__fdiv_rn(-q2, HH));
                acc = __fadd_rn(acc, -__fmul_rn(d, wt));
            }
        }
        if (lane == 0) atomicAdd(out, acc * 0.0625f);   // mean over B=16
    }
}

// ---------------- Host: JAX threefry2x32 (partitionable mode) ---------------
static inline uint32_t rotl32(uint32_t x, uint32_t d) { return (x << d) | (x >> (32 - d)); }

static void tf2x32(uint32_t k0, uint32_t k1, uint32_t x0, uint32_t x1,
                   uint32_t& y0, uint32_t& y1) {
    const uint32_t ks[3] = { k0, k1, k0 ^ k1 ^ 0x1BD11BDAu };
    const uint32_t rotA[4] = { 13, 15, 26, 6 };
    const uint32_t rotB[4] = { 17, 29, 16, 24 };
    uint32_t v0 = x0 + ks[0], v1 = x1 + ks[1];
    for (int i = 0; i < 5; ++i) {
        const uint32_t* rot = (i % 2 == 0) ? rotA : rotB;
        for (int j = 0; j < 4; ++j) {
            v0 += v1;
            v1 = rotl32(v1, rot[j]);
            v1 ^= v0;
        }
        v0 += ks[(i + 1) % 3];
        v1 += ks[(i + 2) % 3] + (uint32_t)(i + 1);
    }
    y0 = v0; y1 = v1;
}

extern "C" void kernel_launch(void* const* d_in, const int* in_sizes, int n_in,
                              void* d_out, int out_size, void* d_ws, size_t ws_size,
                              hipStream_t stream) {
    const float* pcs = (const float*)d_in[0];
    float* out = (float*)d_out;

    // ws layout: [0,1280) seeds (int); [2048, 2048+16*20*16*8) slots (u64)
    int* seeds               = (int*)d_ws;
    unsigned long long* slots = (unsigned long long*)((char*)d_ws + 2048);

    // jax.random.key(1) -> threefry key (0,1), partitionable mode:
    //   split foldlike: k2 = threefry((0,1),(0,1)) both words
    //   random_bits: counters (0,i), out = y0 ^ y1; randint span 2^16 -> mask
    uint32_t k2_0, k2_1;
    tf2x32(0u, 1u, 0u, 1u, k2_0, k2_1);
    InitIdx init;
    for (int i = 0; i < NB; ++i) {
        uint32_t y0, y1;
        tf2x32(k2_0, k2_1, 0u, (uint32_t)i, y0, y1);
        init.idx[i] = (int)((y0 ^ y1) & 0xFFFFu);
    }

    hipMemsetAsync(d_ws, 0, 2048 + (size_t)NB * NS * FPB * 8, stream);
    hipMemsetAsync(d_out, 0, sizeof(float), stream);

    hipLaunchKernelGGL(fps_kernel, dim3(NB * FPB), dim3(1024), 0, stream,
                       pcs, seeds, slots, init);
    hipLaunchKernelGGL(knn_kernel, dim3(NB * NS), dim3(1024), 0, stream,
                       pcs, seeds, out);
}

// Round 6
// 118.655 us; speedup vs baseline: 6.7613x; 1.0966x over previous
//
#include <hip/hip_runtime.h>
#include <cstdint>
#include <cfloat>
#include <cmath>

#define NPTS 65536
#define NB 16
#define NS 20
#define KK 10
#define FPB 16      // FPS blocks per batch
#define PPT 4       // points per thread (16 blk * 1024 thr * 4 = 65536)

struct InitIdx { int idx[NB]; };

// ---------------- Kernel 1: distributed FPS (exact JAX semantics) -----------
// 256 blocks (16 per batch) x 1024 threads, 4 points/thread in registers.
// XCD-aware mapping: physical XCD = blockIdx%8 (heuristic); batch b's 16
// blocks all land on XCD b>>1, so the per-step flag-barrier slots stay in
// that XCD's L2 (store->poll ~200cy instead of cross-fabric ~1-2us).
// Correctness is mapping-independent (pure perf heuristic).
// Cross-block argmax per step: leader publishes packed u64
// (fbits(val)<<32 | ~idx -> max = larger val, tie -> smaller idx = JAX argmax
// first-occurrence) via agent-scope relaxed atomic STORE; all blocks poll the
// 16 slots with atomic LOADs (no RMW) and shuffle-reduce the max.
__global__ __launch_bounds__(1024) void fps_kernel(const float* __restrict__ pcs,
                                                   int* __restrict__ seeds,
                                                   unsigned long long* __restrict__ slots,
                                                   InitIdx init) {
    const int u   = blockIdx.x;
    const int xcd = u & 7;
    const int k   = u >> 3;            // 0..31
    const int b   = 2 * xcd + (k >> 4);
    const int j   = k & 15;
    const int t  = threadIdx.x;
    const int lane = t & 63;
    const int w    = t >> 6;
    const float* __restrict__ base = pcs + (size_t)b * NPTS * 3;
    const int pbase = j * 4096 + t;

    float x[PPT], y[PPT], z[PPT], dmv[PPT];
#pragma unroll
    for (int q = 0; q < PPT; ++q) {
        const float* p = base + (size_t)(pbase + q * 1024) * 3;
        x[q] = p[0]; y[q] = p[1]; z[q] = p[2];
        dmv[q] = 1e10f;
    }

    __shared__ float s_val[16];
    __shared__ int   s_idx[16];
    __shared__ int   s_far;

    int far = init.idx[b];

    for (int s = 0; s < NS; ++s) {
        if (j == 0 && t == 0) seeds[b * NS + s] = far;   // seed s = far BEFORE update
        if (s == NS - 1) break;                          // last update/argmax unused

        const float* c = base + (size_t)far * 3;         // uniform, L1/L2 hit
        const float cx = c[0], cy = c[1], cz = c[2];

        float bestv = -1.0f;
        int   besti = 0;
#pragma unroll
        for (int q = 0; q < PPT; ++q) {
            // match XLA: rounded sub/mul, sequential adds, NO fma contraction
            float dx = __fsub_rn(x[q], cx);
            float dy = __fsub_rn(y[q], cy);
            float dz = __fsub_rn(z[q], cz);
            float d  = __fadd_rn(__fadd_rn(__fmul_rn(dx, dx), __fmul_rn(dy, dy)),
                                 __fmul_rn(dz, dz));
            dmv[q] = fminf(dmv[q], d);
            // q ascending = index ascending; strict > keeps first occurrence
            if (dmv[q] > bestv) { bestv = dmv[q]; besti = pbase + q * 1024; }
        }

        // wave argmax (strict >, tie -> smaller index)
#pragma unroll
        for (int off = 32; off >= 1; off >>= 1) {
            float ov = __shfl_down(bestv, off);
            int   oi = __shfl_down(besti, off);
            if (ov > bestv || (ov == bestv && oi < besti)) { bestv = ov; besti = oi; }
        }
        if (lane == 0) { s_val[w] = bestv; s_idx[w] = besti; }
        __syncthreads();

        unsigned long long* sp = slots + ((size_t)(b * NS + s) << 4);
        if (w == 0) {
            if (lane == 0) {
                float bv = s_val[0]; int bi = s_idx[0];
                for (int kk2 = 1; kk2 < 16; ++kk2) {
                    float v = s_val[kk2]; int ii = s_idx[kk2];
                    if (v > bv || (v == bv && ii < bi)) { bv = v; bi = ii; }
                }
                // packed: monotone for bv >= 0; tie -> larger ~idx = smaller idx.
                // Always nonzero (low word = ~idx != 0 for idx < 2^32-1).
                unsigned long long packed =
                    ((unsigned long long)__float_as_uint(bv) << 32) |
                    (unsigned long long)(0xFFFFFFFFu - (unsigned int)bi);
                __hip_atomic_store(&sp[j], packed, __ATOMIC_RELAXED,
                                   __HIP_MEMORY_SCOPE_AGENT);
            }
            // poll: lane l watches slot l&15 (coalesced pure loads, no RMW)
            unsigned long long v;
            do {
                v = __hip_atomic_load(&sp[lane & 15], __ATOMIC_RELAXED,
                                      __HIP_MEMORY_SCOPE_AGENT);
                if (v == 0ULL) __builtin_amdgcn_s_sleep(1);
            } while (v == 0ULL);
            // wave max-reduce of packed keys (split 64-bit shuffle)
#pragma unroll
            for (int off = 32; off >= 1; off >>= 1) {
                unsigned int lo = (unsigned int)(v & 0xFFFFFFFFull);
                unsigned int hi = (unsigned int)(v >> 32);
                unsigned int olo = (unsigned int)__shfl_xor((int)lo, off);
                unsigned int ohi = (unsigned int)__shfl_xor((int)hi, off);
                unsigned long long o = ((unsigned long long)ohi << 32) | olo;
                if (o > v) v = o;
            }
            if (lane == 0)
                s_far = (int)(0xFFFFFFFFu - (unsigned int)(v & 0xFFFFFFFFull));
        }
        __syncthreads();
        far = s_far;
    }
}

// ---------------- Kernel 2: per-seed 11 smallest distances + repulsion ------
// One block (1024 thr) per (batch, seed), XCD-mapped so batch b's 20 blocks
// run on XCD b>>1 (2 batches x 786KB = 1.6MB working set, L2-resident and
// pre-warmed by fps on the same XCD). Per-thread sorted top-11 of squared
// distances over 64 points, wave-level shuffle merge, single-wave final merge.
// sqrt is monotone -> selection on sq == selection on dist.
__global__ __launch_bounds__(1024) void knn_kernel(const float* __restrict__ pcs,
                                                   const int* __restrict__ seeds,
                                                   float* __restrict__ out) {
    const int u   = blockIdx.x;        // 0..319
    const int xcd = u & 7;
    const int k   = u >> 3;            // 0..39
    const int b   = 2 * xcd + (k & 1);
    const int s   = k >> 1;            // 0..19
    const int p   = b * NS + s;
    const int t = threadIdx.x;
    const int lane = t & 63;
    const int w = t >> 6;              // wave id 0..15
    const float* __restrict__ base = pcs + (size_t)b * NPTS * 3;
    const int sidx = seeds[p];
    const float cx = base[(size_t)sidx * 3 + 0];
    const float cy = base[(size_t)sidx * 3 + 1];
    const float cz = base[(size_t)sidx * 3 + 2];

    float lst[11];
#pragma unroll
    for (int jj = 0; jj < 11; ++jj) lst[jj] = FLT_MAX;

#pragma unroll 8
    for (int i = 0; i < 64; ++i) {
        const int n = i * 1024 + t;
        const float* q = base + (size_t)n * 3;
        float dx = __fsub_rn(q[0], cx);
        float dy = __fsub_rn(q[1], cy);
        float dz = __fsub_rn(q[2], cz);
        float sq = __fadd_rn(__fadd_rn(__fmul_rn(dx, dx), __fmul_rn(dy, dy)),
                             __fmul_rn(dz, dz));
        if (sq < lst[10]) {
            lst[10] = sq;
#pragma unroll
            for (int jj = 10; jj > 0; --jj) {
                float a = lst[jj - 1], c = lst[jj];
                lst[jj - 1] = fminf(a, c);
                lst[jj]     = fmaxf(a, c);
            }
        }
    }

    // ---- wave-level top-11: 11 rounds of (wave-min of heads, pop one copy) --
    __shared__ float s_top[16][11];
    for (int r = 0; r < 11; ++r) {
        float v = lst[0];
#pragma unroll
        for (int off = 32; off >= 1; off >>= 1) v = fminf(v, __shfl_xor(v, off));
        unsigned long long m = __ballot(lst[0] == v);
        if (lane == __ffsll((unsigned long long)m) - 1) {
#pragma unroll
            for (int jj = 0; jj < 10; ++jj) lst[jj] = lst[jj + 1];
            lst[10] = FLT_MAX;
        }
        if (lane == 0) s_top[w][r] = v;
    }
    __syncthreads();

    // ---- final merge: wave 0 merges 16 lists x 11 = 176 values -------------
    if (w == 0) {
        const float* flat = &s_top[0][0];
        float a0 = flat[lane];
        float a1 = flat[lane + 64];
        float a2 = (lane + 128 < 176) ? flat[lane + 128] : FLT_MAX;

        const float HH = (float)(0.01 * 0.01);   // JAX weak-typed scalar H*H
        float acc = 0.0f;
        for (int r = 0; r < 11; ++r) {
            float mymin = fminf(a0, fminf(a1, a2));
            float v = mymin;
#pragma unroll
            for (int off = 32; off >= 1; off >>= 1) v = fminf(v, __shfl_xor(v, off));
            unsigned long long m = __ballot(mymin == v);
            if (lane == __ffsll(m) - 1) {
                if (a0 == v)      a0 = FLT_MAX;
                else if (a1 == v) a1 = FLT_MAX;
                else              a2 = FLT_MAX;
            }
            if (lane == 0 && r >= 1) {           // r==0 is self (dist 0)
                float sq = v;
                float d  = (sq == 0.0f) ? 0.0f : __fsqrt_rn(sq);
                float q2 = __fmul_rn(d, d);
                float wt = expf(__fdiv_rn(-q2, HH));
                acc = __fadd_rn(acc, -__fmul_rn(d, wt));
            }
        }
        if (lane == 0) atomicAdd(out, acc * 0.0625f);   // mean over B=16
    }
}

// ---------------- Host: JAX threefry2x32 (partitionable mode) ---------------
static inline uint32_t rotl32(uint32_t x, uint32_t d) { return (x << d) | (x >> (32 - d)); }

static void tf2x32(uint32_t k0, uint32_t k1, uint32_t x0, uint32_t x1,
                   uint32_t& y0, uint32_t& y1) {
    const uint32_t ks[3] = { k0, k1, k0 ^ k1 ^ 0x1BD11BDAu };
    const uint32_t rotA[4] = { 13, 15, 26, 6 };
    const uint32_t rotB[4] = { 17, 29, 16, 24 };
    uint32_t v0 = x0 + ks[0], v1 = x1 + ks[1];
    for (int i = 0; i < 5; ++i) {
        const uint32_t* rot = (i % 2 == 0) ? rotA : rotB;
        for (int j = 0; j < 4; ++j) {
            v0 += v1;
            v1 = rotl32(v1, rot[j]);
            v1 ^= v0;
        }
        v0 += ks[(i + 1) % 3];
        v1 += ks[(i + 2) % 3] + (uint32_t)(i + 1);
    }
    y0 = v0; y1 = v1;
}

extern "C" void kernel_launch(void* const* d_in, const int* in_sizes, int n_in,
                              void* d_out, int out_size, void* d_ws, size_t ws_size,
                              hipStream_t stream) {
    const float* pcs = (const float*)d_in[0];
    float* out = (float*)d_out;

    // ws layout: [0,1280) seeds (int); [2048, 2048+16*20*16*8) slots (u64)
    int* seeds                = (int*)d_ws;
    unsigned long long* slots = (unsigned long long*)((char*)d_ws + 2048);

    // jax.random.key(1) -> threefry key (0,1), partitionable mode:
    //   split foldlike: k2 = threefry((0,1),(0,1)) both words
    //   random_bits: counters (0,i), out = y0 ^ y1; randint span 2^16 -> mask
    uint32_t k2_0, k2_1;
    tf2x32(0u, 1u, 0u, 1u, k2_0, k2_1);
    InitIdx init;
    for (int i = 0; i < NB; ++i) {
        uint32_t y0, y1;
        tf2x32(k2_0, k2_1, 0u, (uint32_t)i, y0, y1);
        init.idx[i] = (int)((y0 ^ y1) & 0xFFFFu);
    }

    hipMemsetAsync(d_ws, 0, 2048 + (size_t)NB * NS * FPB * 8, stream);
    hipMemsetAsync(d_out, 0, sizeof(float), stream);

    hipLaunchKernelGGL(fps_kernel, dim3(NB * FPB), dim3(1024), 0, stream,
                       pcs, seeds, slots, init);
    hipLaunchKernelGGL(knn_kernel, dim3(NB * NS), dim3(1024), 0, stream,
                       pcs, seeds, out);
}